// Round 1
// baseline (227.444 us; speedup 1.0000x reference)
//
#include <hip/hip_runtime.h>

#define DOUT 128
#define NEG 0.01f

// ---------------- GEMM: h = x @ W + b  (fp32, vector ALU) ----------------
#define BM 64
#define BK 32

__global__ __launch_bounds__(256)
void gemm_h(const float* __restrict__ x, const float* __restrict__ W,
            const float* __restrict__ b, float* __restrict__ h, int N)
{
    __shared__ float Ws[BK][DOUT];   // 16 KB
    __shared__ float Xs[BM][BK];     // 8 KB
    const int tid = threadIdx.x;
    const int tx = tid & 31;         // dim group: dims [tx*4, tx*4+4)
    const int ty = tid >> 5;         // node group: nodes [ty*8, ty*8+8)
    const int row0 = blockIdx.x * BM;

    float acc[8][4];
#pragma unroll
    for (int i = 0; i < 8; ++i)
#pragma unroll
        for (int j = 0; j < 4; ++j) acc[i][j] = 0.f;

    for (int k0 = 0; k0 < DOUT; k0 += BK) {
        // stage W chunk: 32x128 floats = 1024 float4, 4 per thread (coalesced)
#pragma unroll
        for (int i = 0; i < 4; ++i) {
            int q = i * 256 + tid;          // 0..1023
            int r = q >> 5;                 // k row 0..31
            int c = (q & 31) << 2;          // col 0,4,...,124
            *(float4*)&Ws[r][c] = *(const float4*)&W[(size_t)(k0 + r) * DOUT + c];
        }
        // stage x chunk: 64x32 floats = 512 float4, 2 per thread (coalesced)
#pragma unroll
        for (int i = 0; i < 2; ++i) {
            int q = i * 256 + tid;          // 0..511
            int r = q >> 3;                 // node 0..63
            int c = (q & 7) << 2;           // k 0,4,...,28
            int gn = row0 + r;
            float4 v = make_float4(0.f, 0.f, 0.f, 0.f);
            if (gn < N) v = *(const float4*)&x[(size_t)gn * DOUT + k0 + c];
            *(float4*)&Xs[r][c] = v;
        }
        __syncthreads();
#pragma unroll
        for (int k = 0; k < BK; ++k) {
            float4 wv = *(float4*)&Ws[k][tx << 2];
#pragma unroll
            for (int i = 0; i < 8; ++i) {
                float xv = Xs[ty * 8 + i][k];   // 2-way bank alias per wave: free
                acc[i][0] += xv * wv.x;
                acc[i][1] += xv * wv.y;
                acc[i][2] += xv * wv.z;
                acc[i][3] += xv * wv.w;
            }
        }
        __syncthreads();
    }
    const float4 bb = *(const float4*)&b[tx << 2];
#pragma unroll
    for (int i = 0; i < 8; ++i) {
        int gn = row0 + ty * 8 + i;
        if (gn < N) {
            float4 o;
            o.x = acc[i][0] + bb.x;
            o.y = acc[i][1] + bb.y;
            o.z = acc[i][2] + bb.z;
            o.w = acc[i][3] + bb.w;
            *(float4*)&h[(size_t)gn * DOUT + (tx << 2)] = o;
        }
    }
}

// ---------------- per-node attention scalars: s_dst/s_src = h . a_w ----------------
__global__ __launch_bounds__(256)
void s_kernel(const float* __restrict__ h, const float* __restrict__ a_w,
              float* __restrict__ s_dst, float* __restrict__ s_src, int N)
{
    const int lane = threadIdx.x & 63;
    const int wave = threadIdx.x >> 6;
    const int n = blockIdx.x * 4 + wave;
    if (n >= N) return;
    float2 hv = *(const float2*)&h[(size_t)n * DOUT + lane * 2];
    float2 ad = *(const float2*)&a_w[lane * 2];
    float2 as = *(const float2*)&a_w[DOUT + lane * 2];
    float sd = hv.x * ad.x + hv.y * ad.y;
    float ss = hv.x * as.x + hv.y * as.y;
#pragma unroll
    for (int o = 32; o; o >>= 1) {
        sd += __shfl_down(sd, o, 64);
        ss += __shfl_down(ss, o, 64);
    }
    if (lane == 0) { s_dst[n] = sd; s_src[n] = ss; }
}

// ---------------- CSR row offsets from sorted edge_dst ----------------
__global__ void build_offsets(const int* __restrict__ edge_dst,
                              int* __restrict__ offsets, int N, int E)
{
    int e = blockIdx.x * blockDim.x + threadIdx.x;
    if (e >= E) return;
    int d = edge_dst[e];
    int prev = (e == 0) ? -1 : edge_dst[e - 1];
    for (int n = prev + 1; n <= d; ++n) offsets[n] = e;
    if (e == E - 1)
        for (int n = d + 1; n <= N; ++n) offsets[n] = E;
}

// ---------------- segment softmax + weighted aggregation ----------------
#define BUF 1024

__global__ __launch_bounds__(128)
void gat_agg(const int* __restrict__ edge_src, const int* __restrict__ offsets,
             const float* __restrict__ h, const float* __restrict__ s_src,
             const float* __restrict__ s_dst, const float* __restrict__ a_b,
             float* __restrict__ out, int N)
{
    const int n = blockIdx.x;
    const int tid = threadIdx.x;
    __shared__ float buf[BUF];
    __shared__ float red[2];

    const int start = offsets[n];
    const int end = offsets[n + 1];
    const int deg = end - start;
    if (deg == 0) { out[(size_t)n * DOUT + tid] = 0.f; return; }

    const float sdn = s_dst[n] + a_b[0];

    // pass 1: logits -> LDS cache, block max
    float mymax = -3.4e38f;
    for (int e = start + tid; e < end; e += 128) {
        float lg = sdn + s_src[edge_src[e]];
        lg = lg >= 0.f ? lg : NEG * lg;
        int idx = e - start;
        if (idx < BUF) buf[idx] = lg;
        mymax = fmaxf(mymax, lg);
    }
#pragma unroll
    for (int o = 32; o; o >>= 1) mymax = fmaxf(mymax, __shfl_down(mymax, o, 64));
    __syncthreads();
    if ((tid & 63) == 0) red[tid >> 6] = mymax;
    __syncthreads();
    const float m = fmaxf(red[0], red[1]);
    __syncthreads();

    // pass 2: exp + block sum (buf: logit -> exp in place, thread-owned slots)
    float mysum = 0.f;
    for (int e = start + tid; e < end; e += 128) {
        int idx = e - start;
        float lg;
        if (idx < BUF) lg = buf[idx];
        else {
            lg = sdn + s_src[edge_src[e]];
            lg = lg >= 0.f ? lg : NEG * lg;
        }
        float ex = __expf(lg - m);
        if (idx < BUF) buf[idx] = ex;
        mysum += ex;
    }
#pragma unroll
    for (int o = 32; o; o >>= 1) mysum += __shfl_down(mysum, o, 64);
    __syncthreads();
    if ((tid & 63) == 0) red[tid >> 6] = mysum;
    __syncthreads();
    const float inv = 1.f / fmaxf(red[0] + red[1], 1e-16f);

    // pass 3: thread = feature dim; weighted gather of h[src]
    float acc = 0.f;
    for (int e = start; e < end; ++e) {
        int idx = e - start;
        float w;
        if (idx < BUF) w = buf[idx];
        else {
            float lg = sdn + s_src[edge_src[e]];
            lg = lg >= 0.f ? lg : NEG * lg;
            w = __expf(lg - m);
        }
        w *= inv;
        acc += w * h[(size_t)edge_src[e] * DOUT + tid];
    }
    out[(size_t)n * DOUT + tid] = acc;
}

extern "C" void kernel_launch(void* const* d_in, const int* in_sizes, int n_in,
                              void* d_out, int out_size, void* d_ws, size_t ws_size,
                              hipStream_t stream)
{
    const float* x        = (const float*)d_in[0];
    const int*   edge_src = (const int*)d_in[1];
    const int*   edge_dst = (const int*)d_in[2];
    const float* W        = (const float*)d_in[3];
    const float* b        = (const float*)d_in[4];
    const float* a_w      = (const float*)d_in[5];
    const float* a_b      = (const float*)d_in[6];
    const int N = in_sizes[0] / DOUT;
    const int E = in_sizes[1];
    float* out = (float*)d_out;

    char* ws = (char*)d_ws;
    float* h       = (float*)ws;  ws += (size_t)N * DOUT * sizeof(float);
    float* s_dst   = (float*)ws;  ws += (size_t)N * sizeof(float);
    float* s_src   = (float*)ws;  ws += (size_t)N * sizeof(float);
    int*   offsets = (int*)ws;    ws += (size_t)(N + 1) * sizeof(int);

    gemm_h<<<(N + BM - 1) / BM, 256, 0, stream>>>(x, W, b, h, N);
    s_kernel<<<(N + 3) / 4, 256, 0, stream>>>(h, a_w, s_dst, s_src, N);
    build_offsets<<<(E + 255) / 256, 256, 0, stream>>>(edge_dst, offsets, N, E);
    gat_agg<<<N, 128, 0, stream>>>(edge_src, offsets, h, s_src, s_dst, a_b, out, N);
}

// Round 2
// 206.373 us; speedup vs baseline: 1.1021x; 1.1021x over previous
//
#include <hip/hip_runtime.h>

#define DOUT 128
#define NEG 0.01f

// ---------------- GEMM: h = x @ W + b (fp32 vector ALU) + fused s_dst/s_src ----------------
#define BM 64
#define BK 32

__global__ __launch_bounds__(256)
void gemm_h(const float* __restrict__ x, const float* __restrict__ W,
            const float* __restrict__ b, const float* __restrict__ a_w,
            float* __restrict__ h, float* __restrict__ s_dst,
            float* __restrict__ s_src, int N)
{
    __shared__ float Ws[BK][DOUT];   // 16 KB
    __shared__ float Xs[BM][BK];     // 8 KB
    const int tid = threadIdx.x;
    const int tx = tid & 31;         // dim group: dims [tx*4, tx*4+4)
    const int ty = tid >> 5;         // node group: nodes [ty*8, ty*8+8)
    const int row0 = blockIdx.x * BM;

    float acc[8][4];
#pragma unroll
    for (int i = 0; i < 8; ++i)
#pragma unroll
        for (int j = 0; j < 4; ++j) acc[i][j] = 0.f;

    for (int k0 = 0; k0 < DOUT; k0 += BK) {
        // stage W chunk: 32x128 floats = 1024 float4, 4 per thread (coalesced)
#pragma unroll
        for (int i = 0; i < 4; ++i) {
            int q = i * 256 + tid;
            int r = q >> 5;
            int c = (q & 31) << 2;
            *(float4*)&Ws[r][c] = *(const float4*)&W[(size_t)(k0 + r) * DOUT + c];
        }
        // stage x chunk: 64x32 floats = 512 float4, 2 per thread (coalesced)
#pragma unroll
        for (int i = 0; i < 2; ++i) {
            int q = i * 256 + tid;
            int r = q >> 3;
            int c = (q & 7) << 2;
            int gn = row0 + r;
            float4 v = make_float4(0.f, 0.f, 0.f, 0.f);
            if (gn < N) v = *(const float4*)&x[(size_t)gn * DOUT + k0 + c];
            *(float4*)&Xs[r][c] = v;
        }
        __syncthreads();
#pragma unroll
        for (int k = 0; k < BK; k += 4) {
            float4 w0 = *(float4*)&Ws[k + 0][tx << 2];
            float4 w1 = *(float4*)&Ws[k + 1][tx << 2];
            float4 w2 = *(float4*)&Ws[k + 2][tx << 2];
            float4 w3 = *(float4*)&Ws[k + 3][tx << 2];
#pragma unroll
            for (int i = 0; i < 8; ++i) {
                float4 xq = *(float4*)&Xs[ty * 8 + i][k];
                acc[i][0] += xq.x * w0.x + xq.y * w1.x + xq.z * w2.x + xq.w * w3.x;
                acc[i][1] += xq.x * w0.y + xq.y * w1.y + xq.z * w2.y + xq.w * w3.y;
                acc[i][2] += xq.x * w0.z + xq.y * w1.z + xq.z * w2.z + xq.w * w3.z;
                acc[i][3] += xq.x * w0.w + xq.y * w1.w + xq.z * w2.w + xq.w * w3.w;
            }
        }
        __syncthreads();
    }
    const float4 bb   = *(const float4*)&b[tx << 2];
    const float4 aw_d = *(const float4*)&a_w[tx << 2];
    const float4 aw_s = *(const float4*)&a_w[DOUT + (tx << 2)];
#pragma unroll
    for (int i = 0; i < 8; ++i) {
        int gn = row0 + ty * 8 + i;
        float4 o;
        o.x = acc[i][0] + bb.x;
        o.y = acc[i][1] + bb.y;
        o.z = acc[i][2] + bb.z;
        o.w = acc[i][3] + bb.w;
        if (gn < N) *(float4*)&h[(size_t)gn * DOUT + (tx << 2)] = o;
        // fused attention scalars: s = h . a_w (reduce across the 32 tx lanes)
        float sd = o.x * aw_d.x + o.y * aw_d.y + o.z * aw_d.z + o.w * aw_d.w;
        float ss = o.x * aw_s.x + o.y * aw_s.y + o.z * aw_s.z + o.w * aw_s.w;
#pragma unroll
        for (int off = 16; off; off >>= 1) {
            sd += __shfl_xor(sd, off, 32);
            ss += __shfl_xor(ss, off, 32);
        }
        if (tx == 0 && gn < N) { s_dst[gn] = sd; s_src[gn] = ss; }
    }
}

// ---------------- CSR row offsets from sorted edge_dst ----------------
__global__ void build_offsets(const int* __restrict__ edge_dst,
                              int* __restrict__ offsets, int N, int E)
{
    int e = blockIdx.x * blockDim.x + threadIdx.x;
    if (e >= E) return;
    int d = edge_dst[e];
    int prev = (e == 0) ? -1 : edge_dst[e - 1];
    for (int n = prev + 1; n <= d; ++n) offsets[n] = e;
    if (e == E - 1)
        for (int n = d + 1; n <= N; ++n) offsets[n] = E;
}

// ---------------- segment softmax + weighted aggregation (wave per node) ----------------
#define WBUF 256   // cached edges per node; deg beyond this hits the recompute path

__global__ __launch_bounds__(256)
void gat_agg(const int* __restrict__ edge_src, const int* __restrict__ offsets,
             const float* __restrict__ h, const float* __restrict__ s_src,
             const float* __restrict__ s_dst, const float* __restrict__ a_b,
             float* __restrict__ out, int N)
{
    __shared__ float eb_all[4][WBUF];
    __shared__ int   sb_all[4][WBUF];
    const int lane = threadIdx.x & 63;
    const int wv = threadIdx.x >> 6;
    const int n = blockIdx.x * 4 + wv;
    const bool active = (n < N);

    float* eb = eb_all[wv];
    int*   sb = sb_all[wv];

    int start = 0, end = 0;
    float sdn = 0.f;
    if (active) {
        start = offsets[n];
        end = offsets[n + 1];
        sdn = s_dst[n] + a_b[0];
    }
    const int deg = end - start;
    const int cached = deg < WBUF ? deg : WBUF;
    const float2* __restrict__ h2 = (const float2*)h;

    // ---- pass 1: logits (registers) + src cache (LDS) + wave max ----
    float lgr[4];
    float mymax = -3.4e38f;
#pragma unroll
    for (int t = 0; t < 4; ++t) {
        int i = lane + t * 64;
        if (i < cached) {
            int s = edge_src[start + i];
            float lg = sdn + s_src[s];
            lg = lg >= 0.f ? lg : NEG * lg;
            sb[i] = s;
            lgr[t] = lg;
            mymax = fmaxf(mymax, lg);
        }
    }
    for (int i = WBUF + lane; i < deg; i += 64) {     // overflow path (never in practice)
        float lg = sdn + s_src[edge_src[start + i]];
        lg = lg >= 0.f ? lg : NEG * lg;
        mymax = fmaxf(mymax, lg);
    }
#pragma unroll
    for (int o = 32; o; o >>= 1) mymax = fmaxf(mymax, __shfl_xor(mymax, o, 64));

    // ---- pass 2: exp -> LDS, wave sum ----
    float mysum = 0.f;
#pragma unroll
    for (int t = 0; t < 4; ++t) {
        int i = lane + t * 64;
        if (i < cached) {
            float ex = __expf(lgr[t] - mymax);
            eb[i] = ex;
            mysum += ex;
        }
    }
    for (int i = WBUF + lane; i < deg; i += 64) {     // overflow path
        float lg = sdn + s_src[edge_src[start + i]];
        lg = lg >= 0.f ? lg : NEG * lg;
        mysum += __expf(lg - mymax);
    }
#pragma unroll
    for (int o = 32; o; o >>= 1) mysum += __shfl_xor(mysum, o, 64);

    __syncthreads();   // eb/sb visible across lanes (single barrier, uniform)

    // ---- pass 3: weighted gather, 4 rows in flight ----
    float2 a0 = {0.f, 0.f}, a1 = {0.f, 0.f}, a2 = {0.f, 0.f}, a3 = {0.f, 0.f};
    int e = 0;
    for (; e + 4 <= cached; e += 4) {
        int s0 = sb[e], s1 = sb[e + 1], s2 = sb[e + 2], s3 = sb[e + 3];
        float w0 = eb[e], w1 = eb[e + 1], w2 = eb[e + 2], w3 = eb[e + 3];
        float2 v0 = h2[(size_t)s0 * 64 + lane];
        float2 v1 = h2[(size_t)s1 * 64 + lane];
        float2 v2 = h2[(size_t)s2 * 64 + lane];
        float2 v3 = h2[(size_t)s3 * 64 + lane];
        a0.x += w0 * v0.x; a0.y += w0 * v0.y;
        a1.x += w1 * v1.x; a1.y += w1 * v1.y;
        a2.x += w2 * v2.x; a2.y += w2 * v2.y;
        a3.x += w3 * v3.x; a3.y += w3 * v3.y;
    }
    for (; e < cached; ++e) {
        float w = eb[e];
        float2 v = h2[(size_t)sb[e] * 64 + lane];
        a0.x += w * v.x; a0.y += w * v.y;
    }
    for (; e < deg; ++e) {                            // overflow path
        float lg = sdn + s_src[edge_src[start + e]];
        lg = lg >= 0.f ? lg : NEG * lg;
        float w = __expf(lg - mymax);
        float2 v = h2[(size_t)edge_src[start + e] * 64 + lane];
        a0.x += w * v.x; a0.y += w * v.y;
    }

    if (active) {
        const float inv = 1.f / fmaxf(mysum, 1e-16f);
        float2 o;
        o.x = (a0.x + a1.x + a2.x + a3.x) * inv;
        o.y = (a0.y + a1.y + a2.y + a3.y) * inv;
        ((float2*)out)[(size_t)n * 64 + lane] = o;
    }
}

extern "C" void kernel_launch(void* const* d_in, const int* in_sizes, int n_in,
                              void* d_out, int out_size, void* d_ws, size_t ws_size,
                              hipStream_t stream)
{
    const float* x        = (const float*)d_in[0];
    const int*   edge_src = (const int*)d_in[1];
    const int*   edge_dst = (const int*)d_in[2];
    const float* W        = (const float*)d_in[3];
    const float* b        = (const float*)d_in[4];
    const float* a_w      = (const float*)d_in[5];
    const float* a_b      = (const float*)d_in[6];
    const int N = in_sizes[0] / DOUT;
    const int E = in_sizes[1];
    float* out = (float*)d_out;

    char* ws = (char*)d_ws;
    float* h       = (float*)ws;  ws += (size_t)N * DOUT * sizeof(float);
    float* s_dst   = (float*)ws;  ws += (size_t)N * sizeof(float);
    float* s_src   = (float*)ws;  ws += (size_t)N * sizeof(float);
    int*   offsets = (int*)ws;    ws += (size_t)(N + 1) * sizeof(int);

    gemm_h<<<(N + BM - 1) / BM, 256, 0, stream>>>(x, W, b, a_w, h, s_dst, s_src, N);
    build_offsets<<<(E + 255) / 256, 256, 0, stream>>>(edge_dst, offsets, N, E);
    gat_agg<<<(N + 3) / 4, 256, 0, stream>>>(edge_src, offsets, h, s_src, s_dst, a_b, out, N);
}

// Round 3
// 178.487 us; speedup vs baseline: 1.2743x; 1.1562x over previous
//
#include <hip/hip_runtime.h>

#define DOUT 128
#define NEG 0.01f

// ---------------- GEMM: h = x @ W + b (fp32 vector ALU) + fused s_dst/s_src ----
// x tile staged in LDS ONCE (single barrier); W streamed from global (64 KB,
// L1/L2-hot). Thread = 8 nodes x 4 dims.
#define BM 64

__global__ __launch_bounds__(256)
void gemm_h(const float* __restrict__ x, const float* __restrict__ W,
            const float* __restrict__ b, const float* __restrict__ a_w,
            float* __restrict__ h, float* __restrict__ s_dst,
            float* __restrict__ s_src, int N)
{
    __shared__ float Xs[BM][DOUT];   // 32 KB
    const int tid = threadIdx.x;
    const int row0 = blockIdx.x * BM;

    // stage x tile: 64x128 floats = 2048 float4, 8 per thread, coalesced
#pragma unroll
    for (int i = 0; i < 8; ++i) {
        int q = i * 256 + tid;          // 0..2047
        int r = q >> 5;                 // node 0..63
        int c = (q & 31) << 2;          // dim 0,4,...,124
        int gn = row0 + r;
        float4 v = make_float4(0.f, 0.f, 0.f, 0.f);
        if (gn < N) v = *(const float4*)&x[(size_t)gn * DOUT + c];
        *(float4*)&Xs[r][c] = v;
    }
    __syncthreads();

    const int dg = (tid & 31) << 2;     // dim base (4 dims)
    const int r0 = (tid >> 5) << 3;     // node base (8 nodes)

    float acc[8][4];
#pragma unroll
    for (int i = 0; i < 8; ++i)
#pragma unroll
        for (int j = 0; j < 4; ++j) acc[i][j] = 0.f;

    for (int k = 0; k < DOUT; k += 4) {
        // 4 independent W row loads (L1/L2-hot after first touch)
        float4 w0 = *(const float4*)&W[(size_t)(k + 0) * DOUT + dg];
        float4 w1 = *(const float4*)&W[(size_t)(k + 1) * DOUT + dg];
        float4 w2 = *(const float4*)&W[(size_t)(k + 2) * DOUT + dg];
        float4 w3 = *(const float4*)&W[(size_t)(k + 3) * DOUT + dg];
#pragma unroll
        for (int i = 0; i < 8; ++i) {
            float4 xq = *(float4*)&Xs[r0 + i][k];   // wave-broadcast (free)
            acc[i][0] += xq.x * w0.x + xq.y * w1.x + xq.z * w2.x + xq.w * w3.x;
            acc[i][1] += xq.x * w0.y + xq.y * w1.y + xq.z * w2.y + xq.w * w3.y;
            acc[i][2] += xq.x * w0.z + xq.y * w1.z + xq.z * w2.z + xq.w * w3.z;
            acc[i][3] += xq.x * w0.w + xq.y * w1.w + xq.z * w2.w + xq.w * w3.w;
        }
    }

    const float4 bb   = *(const float4*)&b[dg];
    const float4 aw_d = *(const float4*)&a_w[dg];
    const float4 aw_s = *(const float4*)&a_w[DOUT + dg];
#pragma unroll
    for (int i = 0; i < 8; ++i) {
        int gn = row0 + r0 + i;
        float4 o;
        o.x = acc[i][0] + bb.x;
        o.y = acc[i][1] + bb.y;
        o.z = acc[i][2] + bb.z;
        o.w = acc[i][3] + bb.w;
        if (gn < N) *(float4*)&h[(size_t)gn * DOUT + dg] = o;
        // fused attention scalars: s = h . a_w (reduce across the 32 dim lanes)
        float sd = o.x * aw_d.x + o.y * aw_d.y + o.z * aw_d.z + o.w * aw_d.w;
        float ss = o.x * aw_s.x + o.y * aw_s.y + o.z * aw_s.z + o.w * aw_s.w;
#pragma unroll
        for (int off = 16; off; off >>= 1) {
            sd += __shfl_xor(sd, off, 32);
            ss += __shfl_xor(ss, off, 32);
        }
        if ((tid & 31) == 0 && gn < N) { s_dst[gn] = sd; s_src[gn] = ss; }
    }
}

// ---------------- CSR row offsets from sorted edge_dst ----------------
__global__ void build_offsets(const int* __restrict__ edge_dst,
                              int* __restrict__ offsets, int N, int E)
{
    int e = blockIdx.x * blockDim.x + threadIdx.x;
    if (e >= E) return;
    int d = edge_dst[e];
    int prev = (e == 0) ? -1 : edge_dst[e - 1];
    for (int n = prev + 1; n <= d; ++n) offsets[n] = e;
    if (e == E - 1)
        for (int n = d + 1; n <= N; ++n) offsets[n] = E;
}

// ---------------- segment softmax + weighted aggregation (wave per node) ----------------
#define WBUF 256   // cached edges per node; deg beyond this hits the recompute path

__global__ __launch_bounds__(256)
void gat_agg(const int* __restrict__ edge_src, const int* __restrict__ offsets,
             const float* __restrict__ h, const float* __restrict__ s_src,
             const float* __restrict__ s_dst, const float* __restrict__ a_b,
             float* __restrict__ out, int N)
{
    __shared__ float eb_all[4][WBUF];
    __shared__ int   sb_all[4][WBUF];
    const int lane = threadIdx.x & 63;
    const int wv = threadIdx.x >> 6;
    const int n = blockIdx.x * 4 + wv;
    const bool active = (n < N);

    float* eb = eb_all[wv];
    int*   sb = sb_all[wv];

    int start = 0, end = 0;
    float sdn = 0.f;
    if (active) {
        start = offsets[n];
        end = offsets[n + 1];
        sdn = s_dst[n] + a_b[0];
    }
    const int deg = end - start;
    const int cached = deg < WBUF ? deg : WBUF;
    const float2* __restrict__ h2 = (const float2*)h;

    // ---- pass 1: logits (registers) + src cache (LDS) + wave max ----
    float lgr[4];
    float mymax = -3.4e38f;
#pragma unroll
    for (int t = 0; t < 4; ++t) {
        int i = lane + t * 64;
        if (i < cached) {
            int s = edge_src[start + i];
            float lg = sdn + s_src[s];
            lg = lg >= 0.f ? lg : NEG * lg;
            sb[i] = s;
            lgr[t] = lg;
            mymax = fmaxf(mymax, lg);
        }
    }
    for (int i = WBUF + lane; i < deg; i += 64) {     // overflow path
        float lg = sdn + s_src[edge_src[start + i]];
        lg = lg >= 0.f ? lg : NEG * lg;
        mymax = fmaxf(mymax, lg);
    }
#pragma unroll
    for (int o = 32; o; o >>= 1) mymax = fmaxf(mymax, __shfl_xor(mymax, o, 64));

    // ---- pass 2: exp -> LDS, wave sum ----
    float mysum = 0.f;
#pragma unroll
    for (int t = 0; t < 4; ++t) {
        int i = lane + t * 64;
        if (i < cached) {
            float ex = __expf(lgr[t] - mymax);
            eb[i] = ex;
            mysum += ex;
        }
    }
    for (int i = WBUF + lane; i < deg; i += 64) {     // overflow path
        float lg = sdn + s_src[edge_src[start + i]];
        lg = lg >= 0.f ? lg : NEG * lg;
        mysum += __expf(lg - mymax);
    }
#pragma unroll
    for (int o = 32; o; o >>= 1) mysum += __shfl_xor(mysum, o, 64);

    __syncthreads();   // eb/sb visible across lanes (single barrier, uniform)

    // ---- pass 3: weighted gather, 4 rows in flight ----
    float2 a0 = {0.f, 0.f}, a1 = {0.f, 0.f}, a2 = {0.f, 0.f}, a3 = {0.f, 0.f};
    int e = 0;
    for (; e + 4 <= cached; e += 4) {
        int s0 = sb[e], s1 = sb[e + 1], s2 = sb[e + 2], s3 = sb[e + 3];
        float w0 = eb[e], w1 = eb[e + 1], w2 = eb[e + 2], w3 = eb[e + 3];
        float2 v0 = h2[(size_t)s0 * 64 + lane];
        float2 v1 = h2[(size_t)s1 * 64 + lane];
        float2 v2 = h2[(size_t)s2 * 64 + lane];
        float2 v3 = h2[(size_t)s3 * 64 + lane];
        a0.x += w0 * v0.x; a0.y += w0 * v0.y;
        a1.x += w1 * v1.x; a1.y += w1 * v1.y;
        a2.x += w2 * v2.x; a2.y += w2 * v2.y;
        a3.x += w3 * v3.x; a3.y += w3 * v3.y;
    }
    for (; e < cached; ++e) {
        float w = eb[e];
        float2 v = h2[(size_t)sb[e] * 64 + lane];
        a0.x += w * v.x; a0.y += w * v.y;
    }
    for (; e < deg; ++e) {                            // overflow path
        float lg = sdn + s_src[edge_src[start + e]];
        lg = lg >= 0.f ? lg : NEG * lg;
        float w = __expf(lg - mymax);
        float2 v = h2[(size_t)edge_src[start + e] * 64 + lane];
        a0.x += w * v.x; a0.y += w * v.y;
    }

    if (active) {
        const float inv = 1.f / fmaxf(mysum, 1e-16f);
        float2 o;
        o.x = (a0.x + a1.x + a2.x + a3.x) * inv;
        o.y = (a0.y + a1.y + a2.y + a3.y) * inv;
        ((float2*)out)[(size_t)n * 64 + lane] = o;
    }
}

extern "C" void kernel_launch(void* const* d_in, const int* in_sizes, int n_in,
                              void* d_out, int out_size, void* d_ws, size_t ws_size,
                              hipStream_t stream)
{
    const float* x        = (const float*)d_in[0];
    const int*   edge_src = (const int*)d_in[1];
    const int*   edge_dst = (const int*)d_in[2];
    const float* W        = (const float*)d_in[3];
    const float* b        = (const float*)d_in[4];
    const float* a_w      = (const float*)d_in[5];
    const float* a_b      = (const float*)d_in[6];
    const int N = in_sizes[0] / DOUT;
    const int E = in_sizes[1];
    float* out = (float*)d_out;

    char* ws = (char*)d_ws;
    float* h       = (float*)ws;  ws += (size_t)N * DOUT * sizeof(float);
    float* s_dst   = (float*)ws;  ws += (size_t)N * sizeof(float);
    float* s_src   = (float*)ws;  ws += (size_t)N * sizeof(float);
    int*   offsets = (int*)ws;    ws += (size_t)(N + 1) * sizeof(int);

    gemm_h<<<(N + BM - 1) / BM, 256, 0, stream>>>(x, W, b, a_w, h, s_dst, s_src, N);
    build_offsets<<<(E + 255) / 256, 256, 0, stream>>>(edge_dst, offsets, N, E);
    gat_agg<<<(N + 3) / 4, 256, 0, stream>>>(edge_src, offsets, h, s_src, s_dst, a_b, out, N);
}